// Round 1
// baseline (368.351 us; speedup 1.0000x reference)
//
#include <hip/hip_runtime.h>
#include <hip/hip_bf16.h>

// Problem constants
constexpr int Bc = 65536;
constexpr int Kc = 16;
constexpr int Hc = 128;
constexpr int Dc = 64;
constexpr int Zc = 16;

constexpr int NSLOT = Bc + 1024;      // padded slot space (max padding <= 960)
constexpr int NBLK  = NSLOT / 64;     // 1040 head blocks

// ---------------------------------------------------------------------------
// Generic 128-out layer: bufIn [IN][64] (LDS) @ W [IN][128] (+bias, ReLU)
// -> bufOut [128][64] (LDS). 256 threads: jg=tx&15 covers 8 outputs,
// sg=tx>>4 covers 4 samples. 32 FMA per i-iteration per thread.
// ---------------------------------------------------------------------------
template<int IN>
__device__ __forceinline__ void layer_128(const float* bufIn,
                                          const float* __restrict__ W,
                                          const float* __restrict__ bias,
                                          float* bufOut, int tx)
{
    const int jg = tx & 15;
    const int sg = tx >> 4;
    const int j0 = jg << 3;   // 8 outputs
    const int sb = sg << 2;   // 4 samples

    float acc[4][8];
#pragma unroll
    for (int s = 0; s < 4; ++s)
#pragma unroll
        for (int j = 0; j < 8; ++j) acc[s][j] = 0.0f;

#pragma unroll 4
    for (int i = 0; i < IN; ++i) {
        const float4 h4 = *(const float4*)(bufIn + i * 64 + sb);
        const float4 w0 = *(const float4*)(W + i * 128 + j0);
        const float4 w1 = *(const float4*)(W + i * 128 + j0 + 4);
        const float hs[4] = {h4.x, h4.y, h4.z, h4.w};
        const float ws[8] = {w0.x, w0.y, w0.z, w0.w, w1.x, w1.y, w1.z, w1.w};
#pragma unroll
        for (int s = 0; s < 4; ++s)
#pragma unroll
            for (int j = 0; j < 8; ++j)
                acc[s][j] = fmaf(hs[s], ws[j], acc[s][j]);
    }

    const float4 b0 = *(const float4*)(bias + j0);
    const float4 b1 = *(const float4*)(bias + j0 + 4);
    const float bs[8] = {b0.x, b0.y, b0.z, b0.w, b1.x, b1.y, b1.z, b1.w};
#pragma unroll
    for (int j = 0; j < 8; ++j) {
        float4 v;
        v.x = fmaxf(acc[0][j] + bs[j], 0.0f);
        v.y = fmaxf(acc[1][j] + bs[j], 0.0f);
        v.z = fmaxf(acc[2][j] + bs[j], 0.0f);
        v.w = fmaxf(acc[3][j] + bs[j], 0.0f);
        *(float4*)(bufOut + (j0 + j) * 64 + sb) = v;
    }
}

// ---------------------------------------------------------------------------
// Backbone: z[B,16] -> 4 x (Linear+ReLU) -> h[B,128] (global ws)
// ---------------------------------------------------------------------------
__global__ __launch_bounds__(256, 2) void backbone_kernel(
    const float* __restrict__ z,
    const float* __restrict__ bw0, const float* __restrict__ bb0,
    const float* __restrict__ bw1, const float* __restrict__ bb1,
    const float* __restrict__ bw2, const float* __restrict__ bb2,
    const float* __restrict__ bw3, const float* __restrict__ bb3,
    float* __restrict__ hout)
{
    __shared__ float bufA[128 * 64];
    __shared__ float bufB[128 * 64];
    const int tx = threadIdx.x;
    const int s0 = blockIdx.x * 64;

    // load z tile -> bufA [i][s], i < 16
    {
        const int s = tx >> 2;     // 0..63
        const int q = tx & 3;      // i-range q*4 .. q*4+3
        const float4 zv = *(const float4*)(z + (size_t)(s0 + s) * Zc + q * 4);
        bufA[(q * 4 + 0) * 64 + s] = zv.x;
        bufA[(q * 4 + 1) * 64 + s] = zv.y;
        bufA[(q * 4 + 2) * 64 + s] = zv.z;
        bufA[(q * 4 + 3) * 64 + s] = zv.w;
    }
    __syncthreads();

    layer_128<16>(bufA, bw0, bb0, bufB, tx);  __syncthreads();
    layer_128<128>(bufB, bw1, bb1, bufA, tx); __syncthreads();
    layer_128<128>(bufA, bw2, bb2, bufB, tx); __syncthreads();

    // last backbone layer: bufB -> global hout [s][128], with ReLU
    {
        const int jg = tx & 15;
        const int sg = tx >> 4;
        const int j0 = jg << 3;
        const int sb = sg << 2;
        float acc[4][8];
#pragma unroll
        for (int s = 0; s < 4; ++s)
#pragma unroll
            for (int j = 0; j < 8; ++j) acc[s][j] = 0.0f;
#pragma unroll 4
        for (int i = 0; i < 128; ++i) {
            const float4 h4 = *(const float4*)(bufB + i * 64 + sb);
            const float4 w0 = *(const float4*)(bw3 + i * 128 + j0);
            const float4 w1 = *(const float4*)(bw3 + i * 128 + j0 + 4);
            const float hs[4] = {h4.x, h4.y, h4.z, h4.w};
            const float ws[8] = {w0.x, w0.y, w0.z, w0.w, w1.x, w1.y, w1.z, w1.w};
#pragma unroll
            for (int s = 0; s < 4; ++s)
#pragma unroll
                for (int j = 0; j < 8; ++j)
                    acc[s][j] = fmaf(hs[s], ws[j], acc[s][j]);
        }
        const float4 b0 = *(const float4*)(bb3 + j0);
        const float4 b1 = *(const float4*)(bb3 + j0 + 4);
        const float bs[8] = {b0.x, b0.y, b0.z, b0.w, b1.x, b1.y, b1.z, b1.w};
#pragma unroll
        for (int s = 0; s < 4; ++s) {
            float4 v0, v1;
            v0.x = fmaxf(acc[s][0] + bs[0], 0.0f);
            v0.y = fmaxf(acc[s][1] + bs[1], 0.0f);
            v0.z = fmaxf(acc[s][2] + bs[2], 0.0f);
            v0.w = fmaxf(acc[s][3] + bs[3], 0.0f);
            v1.x = fmaxf(acc[s][4] + bs[4], 0.0f);
            v1.y = fmaxf(acc[s][5] + bs[5], 0.0f);
            v1.z = fmaxf(acc[s][6] + bs[6], 0.0f);
            v1.w = fmaxf(acc[s][7] + bs[7], 0.0f);
            float* dst = hout + (size_t)(s0 + sb + s) * Hc + j0;
            *(float4*)(dst)     = v0;
            *(float4*)(dst + 4) = v1;
        }
    }
}

// ---------------------------------------------------------------------------
// Expert sort: histogram -> aligned offsets + block map -> scatter
// ---------------------------------------------------------------------------
__global__ void hist_kernel(const int* __restrict__ y, int* __restrict__ counts)
{
    __shared__ int lc[Kc];
    if (threadIdx.x < Kc) lc[threadIdx.x] = 0;
    __syncthreads();
    const int b = blockIdx.x * 256 + threadIdx.x;
    atomicAdd(&lc[y[b]], 1);
    __syncthreads();
    if (threadIdx.x < Kc) atomicAdd(&counts[threadIdx.x], lc[threadIdx.x]);
}

__global__ void offsets_kernel(const int* __restrict__ counts,
                               int* __restrict__ aligned_off,
                               int* __restrict__ map)
{
    __shared__ int ao[Kc + 1];
    if (threadIdx.x == 0) {
        int acc = 0;
        for (int e = 0; e < Kc; ++e) {
            ao[e] = acc;
            acc += (counts[e] + 63) & ~63;
        }
        ao[Kc] = acc;
        for (int e = 0; e <= Kc; ++e) aligned_off[e] = ao[e];
    }
    __syncthreads();
    for (int blk = threadIdx.x; blk < NBLK; blk += 256) {
        const int pos = blk * 64;
        int e = -1;
        for (int k = 0; k < Kc; ++k)
            if (pos >= ao[k] && pos < ao[k + 1]) e = k;
        map[blk] = e;
    }
}

__global__ void scatter_kernel(const int* __restrict__ y,
                               const int* __restrict__ aligned_off,
                               int* __restrict__ cursor,
                               int* __restrict__ idx)
{
    __shared__ int lc[Kc];
    __shared__ int lbase[Kc];
    if (threadIdx.x < Kc) lc[threadIdx.x] = 0;
    __syncthreads();
    const int b = blockIdx.x * 256 + threadIdx.x;
    const int e = y[b];
    const int r = atomicAdd(&lc[e], 1);
    __syncthreads();
    if (threadIdx.x < Kc)
        lbase[threadIdx.x] = atomicAdd(&cursor[threadIdx.x], lc[threadIdx.x]);
    __syncthreads();
    idx[aligned_off[e] + lbase[e] + r] = b;
}

// ---------------------------------------------------------------------------
// Heads: one block = 64 samples of ONE expert. 3 x (128->128 ReLU) + 128->64.
// ---------------------------------------------------------------------------
__global__ __launch_bounds__(256, 2) void heads_kernel(
    const float* __restrict__ h, const int* __restrict__ idx,
    const int* __restrict__ counts, const int* __restrict__ aligned_off,
    const int* __restrict__ map,
    const float* __restrict__ hw0, const float* __restrict__ hb0,
    const float* __restrict__ hw1, const float* __restrict__ hb1,
    const float* __restrict__ hw2, const float* __restrict__ hb2,
    const float* __restrict__ hw3, const float* __restrict__ hb3,
    float* __restrict__ out)
{
    __shared__ float bufA[128 * 64];
    __shared__ float bufB[128 * 64];
    __shared__ int sidx[64];

    const int blk = blockIdx.x;
    const int e = map[blk];
    if (e < 0) return;
    const int tx = threadIdx.x;
    const int base = blk * 64;
    const int local0 = base - aligned_off[e];
    const int nvalid = min(64, counts[e] - local0);

    if (tx < 64) sidx[tx] = (tx < nvalid) ? idx[base + tx] : -1;
    __syncthreads();

    // gather h rows -> bufA [i][s]
    {
        const int s = tx >> 2;
        const int q = tx & 3;
        const int b = sidx[s];
#pragma unroll
        for (int c = 0; c < 8; ++c) {
            const int i = q * 32 + c * 4;
            float4 v;
            if (b >= 0) v = *(const float4*)(h + (size_t)b * Hc + i);
            else        { v.x = v.y = v.z = v.w = 0.0f; }
            bufA[(i + 0) * 64 + s] = v.x;
            bufA[(i + 1) * 64 + s] = v.y;
            bufA[(i + 2) * 64 + s] = v.z;
            bufA[(i + 3) * 64 + s] = v.w;
        }
    }
    __syncthreads();

    const size_t we = (size_t)e * Hc * Hc;
    layer_128<128>(bufA, hw0 + we, hb0 + e * Hc, bufB, tx); __syncthreads();
    layer_128<128>(bufB, hw1 + we, hb1 + e * Hc, bufA, tx); __syncthreads();
    layer_128<128>(bufA, hw2 + we, hb2 + e * Hc, bufB, tx); __syncthreads();

    // final layer: 128 -> 64, no ReLU, scatter to out[b][0..63]
    {
        const int jg = tx & 15;     // 16 groups x 4 outputs = 64
        const int sg = tx >> 4;
        const int j0 = jg << 2;
        const int sb = sg << 2;
        const float* W = hw3 + (size_t)e * Hc * Dc;
        float acc[4][4];
#pragma unroll
        for (int s = 0; s < 4; ++s)
#pragma unroll
            for (int j = 0; j < 4; ++j) acc[s][j] = 0.0f;
#pragma unroll 4
        for (int i = 0; i < 128; ++i) {
            const float4 h4 = *(const float4*)(bufB + i * 64 + sb);
            const float4 w  = *(const float4*)(W + i * 64 + j0);
            const float hs[4] = {h4.x, h4.y, h4.z, h4.w};
            const float ws[4] = {w.x, w.y, w.z, w.w};
#pragma unroll
            for (int s = 0; s < 4; ++s)
#pragma unroll
                for (int j = 0; j < 4; ++j)
                    acc[s][j] = fmaf(hs[s], ws[j], acc[s][j]);
        }
        const float4 bv = *(const float4*)(hb3 + e * Dc + j0);
#pragma unroll
        for (int s = 0; s < 4; ++s) {
            const int b = sidx[sb + s];
            if (b >= 0) {
                float4 v;
                v.x = acc[s][0] + bv.x;
                v.y = acc[s][1] + bv.y;
                v.z = acc[s][2] + bv.z;
                v.w = acc[s][3] + bv.w;
                *(float4*)(out + (size_t)b * Dc + j0) = v;
            }
        }
    }
}

// ---------------------------------------------------------------------------
extern "C" void kernel_launch(void* const* d_in, const int* in_sizes, int n_in,
                              void* d_out, int out_size, void* d_ws, size_t ws_size,
                              hipStream_t stream)
{
    const float* z   = (const float*)d_in[0];
    const int*   y   = (const int*)d_in[1];
    const float* bw0 = (const float*)d_in[2];
    const float* bb0 = (const float*)d_in[3];
    const float* bw1 = (const float*)d_in[4];
    const float* bb1 = (const float*)d_in[5];
    const float* bw2 = (const float*)d_in[6];
    const float* bb2 = (const float*)d_in[7];
    const float* bw3 = (const float*)d_in[8];
    const float* bb3 = (const float*)d_in[9];
    const float* hw0 = (const float*)d_in[10];
    const float* hb0 = (const float*)d_in[11];
    const float* hw1 = (const float*)d_in[12];
    const float* hb1 = (const float*)d_in[13];
    const float* hw2 = (const float*)d_in[14];
    const float* hb2 = (const float*)d_in[15];
    const float* hw3 = (const float*)d_in[16];
    const float* hb3 = (const float*)d_in[17];
    float* out = (float*)d_out;

    // workspace layout
    float* hbuf = (float*)d_ws;                                   // B*128 floats
    int* idx    = (int*)((char*)d_ws + (size_t)Bc * Hc * 4);      // NSLOT ints
    int* meta   = idx + NSLOT;
    int* counts      = meta;        // 16
    int* cursor      = meta + 16;   // 16
    int* aligned_off = meta + 32;   // 17
    int* map         = meta + 64;   // NBLK

    hipMemsetAsync(counts, 0, 128, stream);   // zero counts + cursor

    backbone_kernel<<<Bc / 64, 256, 0, stream>>>(
        z, bw0, bb0, bw1, bb1, bw2, bb2, bw3, bb3, hbuf);

    hist_kernel<<<Bc / 256, 256, 0, stream>>>(y, counts);
    offsets_kernel<<<1, 256, 0, stream>>>(counts, aligned_off, map);
    scatter_kernel<<<Bc / 256, 256, 0, stream>>>(y, aligned_off, cursor, idx);

    heads_kernel<<<NBLK, 256, 0, stream>>>(
        hbuf, idx, counts, aligned_off, map,
        hw0, hb0, hw1, hb1, hw2, hb2, hw3, hb3, out);
}

// Round 2
// 207.669 us; speedup vs baseline: 1.7737x; 1.7737x over previous
//
#include <hip/hip_runtime.h>
#include <hip/hip_bf16.h>

// ---------------------------------------------------------------------------
// MappingNetwork: backbone 4x(Linear+ReLU) [16->128, 3x 128->128], then the
// selected expert head only (4 layers, last no-ReLU, 128->64).
// Compute: MFMA f32_32x32x16_f16 with exact 3-term f16 split
//   x*w ~= xhi*whi + xhi*wlo + xlo*whi   (f16 products exact in fp32 acc)
// Operand swap: mfma(Wfrag, ActFrag, acc) -> D[lane&31]=sample, regs=feature.
// ---------------------------------------------------------------------------

typedef _Float16 f16;
typedef __attribute__((ext_vector_type(4)))  _Float16 f16x4;
typedef __attribute__((ext_vector_type(8)))  _Float16 f16x8;
typedef __attribute__((ext_vector_type(16))) float    f32x16;

#define MFMA(a, b, c) __builtin_amdgcn_mfma_f32_32x32x16_f16((a), (b), (c), 0, 0, 0)

constexpr int Bc = 65536;
constexpr int Kc = 16;     // experts
constexpr int Hc = 128;
constexpr int Dc = 64;

constexpr int SB    = 128;               // samples per block
constexpr int PADK  = 136;               // f16 row stride (68 words: frag reads at b128 floor)
constexpr int NSLOT = Bc + Kc * SB;      // 67584
constexpr int NBLK  = NSLOT / SB;        // 528

// ws element counts (f16) for split/transposed weights
constexpr int BBW_F16 = 2048 + 3 * 16384;            // 51200  (l0 [128][16], l1-3 [128][128])
constexpr int HWE_F16 = 3 * 16384 + 8192;            // 57344 per expert (l0-2 [128][128], l3 [64][128])

__device__ __forceinline__ f32x16 zero16() {
    f32x16 z;
#pragma unroll
    for (int i = 0; i < 16; ++i) z[i] = 0.0f;
    return z;
}

// ---------------------------------------------------------------------------
// One 128->128 Linear+ReLU layer on a 128-sample LDS tile.
// Wt layout: [n][KD] f16, k-fast (KD = KSTEPS*16). 4 waves: (wm, wn).
// Whi preloaded to regs (n-half: 2 n-tiles x KSTEPS frags); Wlo streamed.
// ---------------------------------------------------------------------------
template<int KSTEPS>
__device__ __forceinline__ void mfma_layer(
    const f16* __restrict__ WHi, const f16* __restrict__ WLo,
    const float* __restrict__ bias,
    f16* AH, f16* AL, int tx)
{
    constexpr int KD = KSTEPS * 16;
    const int lane = tx & 63, l31 = lane & 31, bh = lane >> 5;
    const int wid = tx >> 6, wm = wid >> 1, wn = wid & 1;

    // preload Whi fragments: A-operand lane layout A[row=l31][k=8*bh+idx]
    f16x8 whi[2][KSTEPS];
#pragma unroll
    for (int nt = 0; nt < 2; ++nt) {
        const f16* wp = WHi + (size_t)(64 * wn + 32 * nt + l31) * KD + 8 * bh;
#pragma unroll
        for (int ks = 0; ks < KSTEPS; ++ks)
            whi[nt][ks] = *(const f16x8*)(wp + ks * 16);
    }

    f32x16 acc[2][2];
#pragma unroll
    for (int mt = 0; mt < 2; ++mt)
#pragma unroll
        for (int nt = 0; nt < 2; ++nt) acc[mt][nt] = zero16();

#pragma unroll
    for (int ks = 0; ks < KSTEPS; ++ks) {
        const f16x8 wlo0 = *(const f16x8*)(WLo + (size_t)(64 * wn + l31) * KD + ks * 16 + 8 * bh);
        const f16x8 wlo1 = *(const f16x8*)(WLo + (size_t)(64 * wn + 32 + l31) * KD + ks * 16 + 8 * bh);
#pragma unroll
        for (int mt = 0; mt < 2; ++mt) {
            const int m = 32 * (2 * wm + mt) + l31;
            const f16x8 ah = *(const f16x8*)(AH + m * PADK + ks * 16 + 8 * bh);
            const f16x8 al = *(const f16x8*)(AL + m * PADK + ks * 16 + 8 * bh);
            acc[mt][0] = MFMA(whi[0][ks], ah, acc[mt][0]);
            acc[mt][1] = MFMA(whi[1][ks], ah, acc[mt][1]);
            acc[mt][0] = MFMA(wlo0,       ah, acc[mt][0]);
            acc[mt][1] = MFMA(wlo1,       ah, acc[mt][1]);
            acc[mt][0] = MFMA(whi[0][ks], al, acc[mt][0]);
            acc[mt][1] = MFMA(whi[1][ks], al, acc[mt][1]);
        }
    }
    __syncthreads();   // all reads of AH/AL done before overwrite

    // epilogue: bias + ReLU + f16 hi/lo split, write next-layer activations.
    // D layout: lane col = m-local (l31); reg r -> n-local = (r&3)+8*(r>>2)+4*bh
#pragma unroll
    for (int mt = 0; mt < 2; ++mt) {
        const int m = 32 * (2 * wm + mt) + l31;
#pragma unroll
        for (int nt = 0; nt < 2; ++nt) {
#pragma unroll
            for (int rg = 0; rg < 4; ++rg) {
                const int nb = 64 * wn + 32 * nt + 8 * rg + 4 * bh;
                const float4 bv = *(const float4*)(bias + nb);
                const float bb[4] = {bv.x, bv.y, bv.z, bv.w};
                f16x4 h4, l4;
#pragma unroll
                for (int j = 0; j < 4; ++j) {
                    float v = acc[mt][nt][rg * 4 + j] + bb[j];
                    v = fmaxf(v, 0.0f);
                    const f16 hi = (f16)v;
                    h4[j] = hi;
                    l4[j] = (f16)(v - (float)hi);
                }
                *(f16x4*)(AH + m * PADK + nb) = h4;
                *(f16x4*)(AL + m * PADK + nb) = l4;
            }
        }
    }
    __syncthreads();
}

// ---------------------------------------------------------------------------
// Backbone: z[B,16] -> 4 layers -> h (split f16 hi/lo) to global
// ---------------------------------------------------------------------------
__global__ __launch_bounds__(256, 2) void backbone_mfma(
    const float* __restrict__ z,
    const f16* __restrict__ bbH, const f16* __restrict__ bbL,
    const float* __restrict__ bb0, const float* __restrict__ bb1,
    const float* __restrict__ bb2, const float* __restrict__ bb3,
    f16* __restrict__ hHi, f16* __restrict__ hLo)
{
    __shared__ f16 AH[128 * PADK];
    __shared__ f16 AL[128 * PADK];
    const int tx = threadIdx.x;
    const int s0 = blockIdx.x * SB;

    // stage z tile: row m = tx>>1, half = tx&1 covers cols hf*8..hf*8+7
    {
        const int m = tx >> 1, hf = tx & 1;
        const float4 z0 = *(const float4*)(z + (size_t)(s0 + m) * 16 + hf * 8);
        const float4 z1 = *(const float4*)(z + (size_t)(s0 + m) * 16 + hf * 8 + 4);
        const float zv[8] = {z0.x, z0.y, z0.z, z0.w, z1.x, z1.y, z1.z, z1.w};
        f16x8 hi8, lo8;
#pragma unroll
        for (int j = 0; j < 8; ++j) {
            const f16 h = (f16)zv[j];
            hi8[j] = h;
            lo8[j] = (f16)(zv[j] - (float)h);
        }
        *(f16x8*)(AH + m * PADK + hf * 8) = hi8;
        *(f16x8*)(AL + m * PADK + hf * 8) = lo8;
    }
    __syncthreads();

    mfma_layer<1>(bbH,         bbL,         bb0, AH, AL, tx);
    mfma_layer<8>(bbH + 2048,  bbL + 2048,  bb1, AH, AL, tx);
    mfma_layer<8>(bbH + 18432, bbL + 18432, bb2, AH, AL, tx);
    mfma_layer<8>(bbH + 34816, bbL + 34816, bb3, AH, AL, tx);

    // write h hi/lo, coalesced
    {
        const int m = tx >> 1, hf = tx & 1;
#pragma unroll
        for (int j = 0; j < 8; ++j) {
            *(f16x8*)(hHi + (size_t)(s0 + m) * 128 + hf * 64 + j * 8) =
                *(const f16x8*)(AH + m * PADK + hf * 64 + j * 8);
            *(f16x8*)(hLo + (size_t)(s0 + m) * 128 + hf * 64 + j * 8) =
                *(const f16x8*)(AL + m * PADK + hf * 64 + j * 8);
        }
    }
}

// ---------------------------------------------------------------------------
// Expert sort (pad to 128): histogram -> aligned offsets + block map -> scatter
// ---------------------------------------------------------------------------
__global__ void hist_kernel(const int* __restrict__ y, int* __restrict__ counts)
{
    __shared__ int lc[Kc];
    if (threadIdx.x < Kc) lc[threadIdx.x] = 0;
    __syncthreads();
    const int b = blockIdx.x * 256 + threadIdx.x;
    atomicAdd(&lc[y[b]], 1);
    __syncthreads();
    if (threadIdx.x < Kc) atomicAdd(&counts[threadIdx.x], lc[threadIdx.x]);
}

__global__ void offsets_kernel(const int* __restrict__ counts,
                               int* __restrict__ aligned_off,
                               int* __restrict__ map)
{
    __shared__ int ao[Kc + 1];
    if (threadIdx.x == 0) {
        int acc = 0;
        for (int e = 0; e < Kc; ++e) {
            ao[e] = acc;
            acc += (counts[e] + SB - 1) & ~(SB - 1);
        }
        ao[Kc] = acc;
        for (int e = 0; e <= Kc; ++e) aligned_off[e] = ao[e];
    }
    __syncthreads();
    for (int blk = threadIdx.x; blk < NBLK; blk += 256) {
        const int pos = blk * SB;
        int e = -1;
        for (int k = 0; k < Kc; ++k)
            if (pos >= ao[k] && pos < ao[k + 1]) e = k;
        map[blk] = e;
    }
}

__global__ void scatter_kernel(const int* __restrict__ y,
                               const int* __restrict__ aligned_off,
                               int* __restrict__ cursor,
                               int* __restrict__ idx)
{
    __shared__ int lc[Kc];
    __shared__ int lbase[Kc];
    if (threadIdx.x < Kc) lc[threadIdx.x] = 0;
    __syncthreads();
    const int b = blockIdx.x * 256 + threadIdx.x;
    const int e = y[b];
    const int r = atomicAdd(&lc[e], 1);
    __syncthreads();
    if (threadIdx.x < Kc)
        lbase[threadIdx.x] = atomicAdd(&cursor[threadIdx.x], lc[threadIdx.x]);
    __syncthreads();
    idx[aligned_off[e] + lbase[e] + r] = b;
}

// ---------------------------------------------------------------------------
// Heads: one block = 128 samples of one expert. 3x(128->128 ReLU) + 128->64.
// Final layer writes float4 directly to out[b]. h_hi lives in the d_out
// region (disjoint rows across blocks; gather precedes stores within block).
// ---------------------------------------------------------------------------
__global__ __launch_bounds__(256, 2) void heads_mfma(
    const f16* hHi, const f16* __restrict__ hLo,
    const int* __restrict__ idx, const int* __restrict__ counts,
    const int* __restrict__ aligned_off, const int* __restrict__ map,
    const f16* __restrict__ hH, const f16* __restrict__ hL,
    const float* __restrict__ hb0, const float* __restrict__ hb1,
    const float* __restrict__ hb2, const float* __restrict__ hb3,
    float* out)
{
    __shared__ f16 AH[128 * PADK];
    __shared__ f16 AL[128 * PADK];
    __shared__ int sidx[SB];

    const int blk = blockIdx.x;
    const int e = map[blk];
    if (e < 0) return;
    const int tx = threadIdx.x;
    const int base = blk * SB;

    if (tx < SB) {
        const int local0 = base - aligned_off[e];
        sidx[tx] = (local0 + tx < counts[e]) ? idx[base + tx] : -1;
    }
    __syncthreads();

    // gather h rows (hi from out-region, lo from ws) -> LDS
    {
        const int m = tx >> 1, hf = tx & 1;
        const int b = sidx[m];
        if (b >= 0) {
#pragma unroll
            for (int j = 0; j < 8; ++j) {
                *(f16x8*)(AH + m * PADK + hf * 64 + j * 8) =
                    *(const f16x8*)(hHi + (size_t)b * 128 + hf * 64 + j * 8);
                *(f16x8*)(AL + m * PADK + hf * 64 + j * 8) =
                    *(const f16x8*)(hLo + (size_t)b * 128 + hf * 64 + j * 8);
            }
        } else {
            f16x8 zz;
#pragma unroll
            for (int j = 0; j < 8; ++j) zz[j] = (f16)0.0f;
#pragma unroll
            for (int j = 0; j < 8; ++j) {
                *(f16x8*)(AH + m * PADK + hf * 64 + j * 8) = zz;
                *(f16x8*)(AL + m * PADK + hf * 64 + j * 8) = zz;
            }
        }
    }
    __syncthreads();

    const size_t we = (size_t)e * HWE_F16;
    mfma_layer<8>(hH + we,         hL + we,         hb0 + e * Hc, AH, AL, tx);
    mfma_layer<8>(hH + we + 16384, hL + we + 16384, hb1 + e * Hc, AH, AL, tx);
    mfma_layer<8>(hH + we + 32768, hL + we + 32768, hb2 + e * Hc, AH, AL, tx);

    // final layer: 128 -> 64, no ReLU, direct float4 stores
    {
        const int lane = tx & 63, l31 = lane & 31, bh = lane >> 5;
        const int wid = tx >> 6, wm = wid >> 1, wn = wid & 1;
        const f16* WHi = hH + we + 49152;
        const f16* WLo = hL + we + 49152;
        const float* bias = hb3 + e * Dc;

        f16x8 whi[8];
        const f16* wp = WHi + (size_t)(32 * wn + l31) * 128 + 8 * bh;
#pragma unroll
        for (int ks = 0; ks < 8; ++ks) whi[ks] = *(const f16x8*)(wp + ks * 16);

        f32x16 acc[2];
        acc[0] = zero16(); acc[1] = zero16();
#pragma unroll
        for (int ks = 0; ks < 8; ++ks) {
            const f16x8 wlo = *(const f16x8*)(WLo + (size_t)(32 * wn + l31) * 128 + ks * 16 + 8 * bh);
#pragma unroll
            for (int mt = 0; mt < 2; ++mt) {
                const int m = 32 * (2 * wm + mt) + l31;
                const f16x8 ah = *(const f16x8*)(AH + m * PADK + ks * 16 + 8 * bh);
                const f16x8 al = *(const f16x8*)(AL + m * PADK + ks * 16 + 8 * bh);
                acc[mt] = MFMA(whi[ks], ah, acc[mt]);
                acc[mt] = MFMA(wlo,     ah, acc[mt]);
                acc[mt] = MFMA(whi[ks], al, acc[mt]);
            }
        }
#pragma unroll
        for (int mt = 0; mt < 2; ++mt) {
            const int b = sidx[32 * (2 * wm + mt) + l31];
            if (b < 0) continue;
#pragma unroll
            for (int rg = 0; rg < 4; ++rg) {
                const int nb = 32 * wn + 8 * rg + 4 * bh;
                const float4 bv = *(const float4*)(bias + nb);
                float4 v;
                v.x = acc[mt][rg * 4 + 0] + bv.x;
                v.y = acc[mt][rg * 4 + 1] + bv.y;
                v.z = acc[mt][rg * 4 + 2] + bv.z;
                v.w = acc[mt][rg * 4 + 3] + bv.w;
                *(float4*)(out + (size_t)b * Dc + nb) = v;
            }
        }
    }
}

// ---------------------------------------------------------------------------
// Weight prep: split fp32 W[k][n] into f16 hi/lo, transposed to Wt[n][k].
// One block per 32x32 tile. 948 blocks total.
// ---------------------------------------------------------------------------
__global__ void prep_w(
    const float* __restrict__ bw0, const float* __restrict__ bw1,
    const float* __restrict__ bw2, const float* __restrict__ bw3,
    const float* __restrict__ hw0, const float* __restrict__ hw1,
    const float* __restrict__ hw2, const float* __restrict__ hw3,
    f16* __restrict__ bbH, f16* __restrict__ bbL,
    f16* __restrict__ hH,  f16* __restrict__ hL)
{
    __shared__ float T[32][33];
    const int id = blockIdx.x;
    const int tx = threadIdx.x;
    const float* src; f16 *dh, *dl;
    int K, N, KD, k0, n0;

    if (id < 52) {
        if (id < 4) {
            src = bw0; dh = bbH; dl = bbL;
            K = 16; N = 128; KD = 16; k0 = 0; n0 = id * 32;
        } else {
            const int t = id - 4;
            const int l = t / 16, tile = t % 16;
            const float* bws[3] = {bw1, bw2, bw3};
            src = bws[l];
            dh = bbH + 2048 + l * 16384;
            dl = bbL + 2048 + l * 16384;
            K = 128; N = 128; KD = 128;
            k0 = (tile >> 2) * 32; n0 = (tile & 3) * 32;
        }
    } else {
        const int t = id - 52;
        const int e = t / 56, r = t % 56;
        if (r < 48) {
            const int l = r / 16, tile = r % 16;
            const float* hws[3] = {hw0, hw1, hw2};
            src = hws[l] + (size_t)e * 16384;
            dh = hH + (size_t)e * HWE_F16 + l * 16384;
            dl = hL + (size_t)e * HWE_F16 + l * 16384;
            K = 128; N = 128; KD = 128;
            k0 = (tile >> 2) * 32; n0 = (tile & 3) * 32;
        } else {
            const int r2 = r - 48;
            src = hw3 + (size_t)e * 8192;
            dh = hH + (size_t)e * HWE_F16 + 49152;
            dl = hL + (size_t)e * HWE_F16 + 49152;
            K = 128; N = 64; KD = 128;
            k0 = (r2 >> 1) * 32; n0 = (r2 & 1) * 32;
        }
    }

    const int c = tx & 31, g = tx >> 5;
#pragma unroll
    for (int i = 0; i < 4; ++i) {
        const int row = g * 4 + i;
        if (k0 + row < K)
            T[c][row] = src[(size_t)(k0 + row) * N + n0 + c];   // T[n-local][k-local]
    }
    __syncthreads();
#pragma unroll
    for (int i = 0; i < 4; ++i) {
        const int n = g * 4 + i;
        if (k0 + c < K) {
            const float v = T[n][c];
            const f16 hi = (f16)v;
            dh[(size_t)(n0 + n) * KD + k0 + c] = hi;
            dl[(size_t)(n0 + n) * KD + k0 + c] = (f16)(v - (float)hi);
        }
    }
}

// ---------------------------------------------------------------------------
extern "C" void kernel_launch(void* const* d_in, const int* in_sizes, int n_in,
                              void* d_out, int out_size, void* d_ws, size_t ws_size,
                              hipStream_t stream)
{
    const float* z   = (const float*)d_in[0];
    const int*   y   = (const int*)d_in[1];
    const float* bw0 = (const float*)d_in[2];
    const float* bb0 = (const float*)d_in[3];
    const float* bw1 = (const float*)d_in[4];
    const float* bb1 = (const float*)d_in[5];
    const float* bw2 = (const float*)d_in[6];
    const float* bb2 = (const float*)d_in[7];
    const float* bw3 = (const float*)d_in[8];
    const float* bb3 = (const float*)d_in[9];
    const float* hw0 = (const float*)d_in[10];
    const float* hb0 = (const float*)d_in[11];
    const float* hw1 = (const float*)d_in[12];
    const float* hb1 = (const float*)d_in[13];
    const float* hw2 = (const float*)d_in[14];
    const float* hb2 = (const float*)d_in[15];
    const float* hw3 = (const float*)d_in[16];
    const float* hb3 = (const float*)d_in[17];
    float* out = (float*)d_out;

    // h_hi (f16 [B][128], 16.78 MB) aliases d_out: backbone fills it fully,
    // heads blocks gather their own rows before storing their own rows.
    f16* hHi = (f16*)d_out;

    // workspace layout
    char* p = (char*)d_ws;
    f16* hLo = (f16*)p;  p += (size_t)Bc * Hc * 2;          // 16.78 MB
    f16* bbH = (f16*)p;  p += (size_t)BBW_F16 * 2;
    f16* bbL = (f16*)p;  p += (size_t)BBW_F16 * 2;
    f16* hH  = (f16*)p;  p += (size_t)Kc * HWE_F16 * 2;
    f16* hL  = (f16*)p;  p += (size_t)Kc * HWE_F16 * 2;
    int* idx = (int*)p;  p += (size_t)NSLOT * 4;
    int* meta        = (int*)p;
    int* counts      = meta;
    int* cursor      = meta + 16;
    int* aligned_off = meta + 32;
    int* map         = meta + 64;

    hipMemsetAsync(counts, 0, 128, stream);   // counts + cursor

    prep_w<<<52 + Kc * 56, 256, 0, stream>>>(bw0, bw1, bw2, bw3,
                                             hw0, hw1, hw2, hw3,
                                             bbH, bbL, hH, hL);

    backbone_mfma<<<Bc / SB, 256, 0, stream>>>(z, bbH, bbL,
                                               bb0, bb1, bb2, bb3, hHi, hLo);

    hist_kernel<<<Bc / 256, 256, 0, stream>>>(y, counts);
    offsets_kernel<<<1, 256, 0, stream>>>(counts, aligned_off, map);
    scatter_kernel<<<Bc / 256, 256, 0, stream>>>(y, aligned_off, cursor, idx);

    heads_mfma<<<NBLK, 256, 0, stream>>>(hHi, hLo, idx, counts, aligned_off, map,
                                         hH, hL, hb0, hb1, hb2, hb3, out);
}

// Round 3
// 193.962 us; speedup vs baseline: 1.8991x; 1.0707x over previous
//
#include <hip/hip_runtime.h>
#include <hip/hip_bf16.h>

// ---------------------------------------------------------------------------
// MappingNetwork: backbone 4x(Linear+ReLU) [16->128, 3x 128->128], then the
// selected expert head only (4 layers, last no-ReLU, 128->64).
// MFMA f32_32x32x16_f16, 2-term weight split with scaled lo:
//   x*w ~= xf16*whi + xf16*(wlo*1024)/1024, separate accumulators
// (wlo ~1e-5 is f16-subnormal; scaling avoids denormal flush; W split exact).
// Activation error: f16 rounding only (~2^-12 rel/layer) -> absmax ~1e-5.
// Operand swap: mfma(Wfrag, ActFrag, acc) -> D lane = sample, regs = feature.
// 3 dispatches: prep_w -> backbone (scatter fused) -> heads.
// ---------------------------------------------------------------------------

typedef _Float16 f16;
typedef __attribute__((ext_vector_type(4)))  _Float16 f16x4;
typedef __attribute__((ext_vector_type(8)))  _Float16 f16x8;
typedef __attribute__((ext_vector_type(16))) float    f32x16;

#define MFMA(a, b, c) __builtin_amdgcn_mfma_f32_32x32x16_f16((a), (b), (c), 0, 0, 0)

constexpr int Bc = 65536;
constexpr int Kc = 16;     // experts
constexpr int Hc = 128;
constexpr int Dc = 64;

constexpr int SB   = 128;            // samples per block
constexpr int PADK = 136;            // f16 row stride (17 x 16B: rotates b128 banks)
constexpr int CAP  = 4608;           // fixed slots/expert = mean 4096 + 8.3 sigma
constexpr int BPE  = CAP / SB;       // 36 head blocks per expert
constexpr int NBLK = Kc * BPE;       // 576

constexpr float INV_LOSCALE = 1.0f / 1024.0f;

// f16 element counts for split/transposed weights
constexpr int BBW_F16 = 2048 + 3 * 16384;   // backbone: l0 [128][16], l1-3 [128][128]
constexpr int HWE_F16 = 3 * 16384 + 8192;   // per expert: l0-2 [128][128], l3 [64][128]

__device__ __forceinline__ f32x16 zero16() {
    f32x16 z;
#pragma unroll
    for (int i = 0; i < 16; ++i) z[i] = 0.0f;
    return z;
}

// ---------------------------------------------------------------------------
// One 128-out Linear+ReLU layer on a 128-sample LDS tile (f16 acts).
// Wt layout: [n][KD] f16 (k-fast). 4 waves: (wm, wn); per wave 2 m-tiles and
// (sequentially) 2 n-tiles. W frags (hi + scaled-lo) fully preloaded per
// n-tile; act frags cached in regs across n-tiles (reads = 16 b128/wave).
// ---------------------------------------------------------------------------
template<int KSTEPS>
__device__ __forceinline__ void mfma_layer2(
    const f16* __restrict__ WHi, const f16* __restrict__ WLo,
    const float* __restrict__ bias,
    f16* AH, int tx)
{
    constexpr int KD = KSTEPS * 16;
    const int lane = tx & 63, l31 = lane & 31, bh = lane >> 5;
    const int wid = tx >> 6, wm = wid >> 1, wn = wid & 1;

    f16x8 af[2][KSTEPS];       // act fragments, cached across n-tiles
    f16x4 outs[2][2][4];       // [nt][mt][rg] results held until barrier

#pragma unroll
    for (int nt = 0; nt < 2; ++nt) {
        // preload W hi + scaled-lo fragments for this n-tile
        f16x8 whi[KSTEPS], wlo[KSTEPS];
        const f16* wp = WHi + (size_t)(64 * wn + 32 * nt + l31) * KD + 8 * bh;
        const f16* wq = WLo + (size_t)(64 * wn + 32 * nt + l31) * KD + 8 * bh;
#pragma unroll
        for (int ks = 0; ks < KSTEPS; ++ks) {
            whi[ks] = *(const f16x8*)(wp + ks * 16);
            wlo[ks] = *(const f16x8*)(wq + ks * 16);
        }

        f32x16 aH[2], aL[2];
#pragma unroll
        for (int mt = 0; mt < 2; ++mt) { aH[mt] = zero16(); aL[mt] = zero16(); }

#pragma unroll
        for (int ks = 0; ks < KSTEPS; ++ks) {
#pragma unroll
            for (int mt = 0; mt < 2; ++mt) {
                if (nt == 0) {
                    const int m = 32 * (2 * wm + mt) + l31;
                    af[mt][ks] = *(const f16x8*)(AH + m * PADK + ks * 16 + 8 * bh);
                }
                aH[mt] = MFMA(whi[ks], af[mt][ks], aH[mt]);
                aL[mt] = MFMA(wlo[ks], af[mt][ks], aL[mt]);
            }
        }

        // combine, bias, ReLU, pack f16 (held in regs until all reads done)
#pragma unroll
        for (int mt = 0; mt < 2; ++mt) {
#pragma unroll
            for (int rg = 0; rg < 4; ++rg) {
                const int nb = 64 * wn + 32 * nt + 8 * rg + 4 * bh;
                const float4 bv = *(const float4*)(bias + nb);
                const float bb[4] = {bv.x, bv.y, bv.z, bv.w};
                f16x4 h4;
#pragma unroll
                for (int j = 0; j < 4; ++j) {
                    const float v = fmaf(aL[mt][rg * 4 + j], INV_LOSCALE,
                                         aH[mt][rg * 4 + j]) + bb[j];
                    h4[j] = (f16)fmaxf(v, 0.0f);
                }
                outs[nt][mt][rg] = h4;
            }
        }
    }

    __syncthreads();   // all waves done reading AH
#pragma unroll
    for (int nt = 0; nt < 2; ++nt)
#pragma unroll
        for (int mt = 0; mt < 2; ++mt) {
            const int m = 32 * (2 * wm + mt) + l31;
#pragma unroll
            for (int rg = 0; rg < 4; ++rg) {
                const int nb = 64 * wn + 32 * nt + 8 * rg + 4 * bh;
                *(f16x4*)(AH + m * PADK + nb) = outs[nt][mt][rg];
            }
        }
    __syncthreads();   // AH ready for next layer
}

// ---------------------------------------------------------------------------
// Backbone + fused scatter: z -> 4 layers -> hHi (f16, in d_out region);
// then per-block expert bucketing into fixed CAP-sized regions.
// ---------------------------------------------------------------------------
__global__ __launch_bounds__(256, 2) void backbone_mfma(
    const float* __restrict__ z, const int* __restrict__ y,
    const f16* __restrict__ bbH, const f16* __restrict__ bbL,
    const float* __restrict__ bb0, const float* __restrict__ bb1,
    const float* __restrict__ bb2, const float* __restrict__ bb3,
    f16* __restrict__ hHi, int* __restrict__ idx, int* __restrict__ cursor)
{
    __shared__ f16 AH[128 * PADK];
    __shared__ int lc[Kc];
    __shared__ int lbase[Kc];
    const int tx = threadIdx.x;
    const int s0 = blockIdx.x * SB;

    // stage z tile as f16: row m = tx>>1, half hf = tx&1 covers cols hf*8..+7
    {
        const int m = tx >> 1, hf = tx & 1;
        const float4 z0 = *(const float4*)(z + (size_t)(s0 + m) * 16 + hf * 8);
        const float4 z1 = *(const float4*)(z + (size_t)(s0 + m) * 16 + hf * 8 + 4);
        const float zv[8] = {z0.x, z0.y, z0.z, z0.w, z1.x, z1.y, z1.z, z1.w};
        f16x8 h8;
#pragma unroll
        for (int j = 0; j < 8; ++j) h8[j] = (f16)zv[j];
        *(f16x8*)(AH + m * PADK + hf * 8) = h8;
    }
    __syncthreads();

    mfma_layer2<1>(bbH,         bbL,         bb0, AH, tx);
    mfma_layer2<8>(bbH + 2048,  bbL + 2048,  bb1, AH, tx);
    mfma_layer2<8>(bbH + 18432, bbL + 18432, bb2, AH, tx);
    mfma_layer2<8>(bbH + 34816, bbL + 34816, bb3, AH, tx);

    // write h (f16), coalesced
    {
        const int m = tx >> 1, hf = tx & 1;
#pragma unroll
        for (int j = 0; j < 8; ++j)
            *(f16x8*)(hHi + (size_t)(s0 + m) * 128 + hf * 64 + j * 8) =
                *(const f16x8*)(AH + m * PADK + hf * 64 + j * 8);
    }

    // fused scatter: LDS-aggregated per-expert ranks, one global atomic each
    if (tx < Kc) lc[tx] = 0;
    __syncthreads();
    int e = 0, r = 0;
    if (tx < SB) {
        e = y[s0 + tx];
        r = atomicAdd(&lc[e], 1);
    }
    __syncthreads();
    if (tx < Kc) lbase[tx] = atomicAdd(&cursor[tx], lc[tx]);
    __syncthreads();
    if (tx < SB) {
        const int slot = lbase[e] + r;
        if (slot < CAP) idx[e * CAP + slot] = s0 + tx;
    }
}

// ---------------------------------------------------------------------------
// Heads: block blk handles samples [blk%BPE * 128 ..) of expert blk/BPE.
// 3x(128->128 ReLU) + 128->64 (no ReLU) -> float4 direct to out[b].
// hHi aliases d_out byte-for-byte per sample row (gather precedes store).
// ---------------------------------------------------------------------------
__global__ __launch_bounds__(256, 2) void heads_mfma(
    const f16* hHi,
    const int* __restrict__ idx, const int* __restrict__ cursor,
    const f16* __restrict__ hH, const f16* __restrict__ hL,
    const float* __restrict__ hb0, const float* __restrict__ hb1,
    const float* __restrict__ hb2, const float* __restrict__ hb3,
    float* out)
{
    __shared__ f16 AH[128 * PADK];
    __shared__ int sidx[SB];

    const int blk = blockIdx.x;
    const int e = blk / BPE;
    const int local0 = (blk % BPE) * SB;
    const int cnt = min(cursor[e], CAP);
    const int nvalid = cnt - local0;
    if (nvalid <= 0) return;                 // uniform: before any barrier

    const int tx = threadIdx.x;
    if (tx < SB) sidx[tx] = (tx < nvalid) ? idx[e * CAP + local0 + tx] : -1;
    __syncthreads();

    // gather h rows (256 B contiguous per sample) -> LDS
    {
        const int m = tx >> 1, hf = tx & 1;
        const int b = sidx[m];
        if (b >= 0) {
#pragma unroll
            for (int j = 0; j < 8; ++j)
                *(f16x8*)(AH + m * PADK + hf * 64 + j * 8) =
                    *(const f16x8*)(hHi + (size_t)b * 128 + hf * 64 + j * 8);
        } else {
            f16x8 zz;
#pragma unroll
            for (int j = 0; j < 8; ++j) zz[j] = (f16)0.0f;
#pragma unroll
            for (int j = 0; j < 8; ++j)
                *(f16x8*)(AH + m * PADK + hf * 64 + j * 8) = zz;
        }
    }
    __syncthreads();

    const size_t we = (size_t)e * HWE_F16;
    mfma_layer2<8>(hH + we,         hL + we,         hb0 + e * Hc, AH, tx);
    mfma_layer2<8>(hH + we + 16384, hL + we + 16384, hb1 + e * Hc, AH, tx);
    mfma_layer2<8>(hH + we + 32768, hL + we + 32768, hb2 + e * Hc, AH, tx);

    // final layer: 128 -> 64, no ReLU, direct float4 stores
    {
        const int lane = tx & 63, l31 = lane & 31, bh = lane >> 5;
        const int wid = tx >> 6, wm = wid >> 1, wn = wid & 1;
        const f16* WHi = hH + we + 49152;
        const f16* WLo = hL + we + 49152;
        const float* bias = hb3 + e * Dc;

        f16x8 whi[8], wlo[8];
        const f16* wp = WHi + (size_t)(32 * wn + l31) * 128 + 8 * bh;
        const f16* wq = WLo + (size_t)(32 * wn + l31) * 128 + 8 * bh;
#pragma unroll
        for (int ks = 0; ks < 8; ++ks) {
            whi[ks] = *(const f16x8*)(wp + ks * 16);
            wlo[ks] = *(const f16x8*)(wq + ks * 16);
        }

        f32x16 aH[2], aL[2];
#pragma unroll
        for (int mt = 0; mt < 2; ++mt) { aH[mt] = zero16(); aL[mt] = zero16(); }
#pragma unroll
        for (int ks = 0; ks < 8; ++ks) {
#pragma unroll
            for (int mt = 0; mt < 2; ++mt) {
                const int m = 32 * (2 * wm + mt) + l31;
                const f16x8 a = *(const f16x8*)(AH + m * PADK + ks * 16 + 8 * bh);
                aH[mt] = MFMA(whi[ks], a, aH[mt]);
                aL[mt] = MFMA(wlo[ks], a, aL[mt]);
            }
        }
#pragma unroll
        for (int mt = 0; mt < 2; ++mt) {
            const int b = sidx[32 * (2 * wm + mt) + l31];
            if (b < 0) continue;
#pragma unroll
            for (int rg = 0; rg < 4; ++rg) {
                const int nb = 32 * wn + 8 * rg + 4 * bh;
                const float4 bv = *(const float4*)(bias + nb);
                float4 v;
                v.x = fmaf(aL[mt][rg * 4 + 0], INV_LOSCALE, aH[mt][rg * 4 + 0]) + bv.x;
                v.y = fmaf(aL[mt][rg * 4 + 1], INV_LOSCALE, aH[mt][rg * 4 + 1]) + bv.y;
                v.z = fmaf(aL[mt][rg * 4 + 2], INV_LOSCALE, aH[mt][rg * 4 + 2]) + bv.z;
                v.w = fmaf(aL[mt][rg * 4 + 3], INV_LOSCALE, aH[mt][rg * 4 + 3]) + bv.w;
                *(float4*)(out + (size_t)b * Dc + nb) = v;
            }
        }
    }
}

// ---------------------------------------------------------------------------
// Weight prep: split fp32 W[k][n] -> f16 hi + f16 (lo*1024), transposed to
// Wt[n][k]. One block per 32x32 tile. Block 0 also zeroes the scatter cursor.
// ---------------------------------------------------------------------------
__global__ void prep_w(
    const float* __restrict__ bw0, const float* __restrict__ bw1,
    const float* __restrict__ bw2, const float* __restrict__ bw3,
    const float* __restrict__ hw0, const float* __restrict__ hw1,
    const float* __restrict__ hw2, const float* __restrict__ hw3,
    f16* __restrict__ bbH, f16* __restrict__ bbL,
    f16* __restrict__ hH,  f16* __restrict__ hL,
    int* __restrict__ cursor)
{
    __shared__ float T[32][33];
    const int id = blockIdx.x;
    const int tx = threadIdx.x;

    if (id == 0 && tx < Kc) cursor[tx] = 0;

    const float* src; f16 *dh, *dl;
    int K, N, KD, k0, n0;

    if (id < 52) {
        if (id < 4) {
            src = bw0; dh = bbH; dl = bbL;
            K = 16; N = 128; KD = 16; k0 = 0; n0 = id * 32;
        } else {
            const int t = id - 4;
            const int l = t / 16, tile = t % 16;
            const float* bws[3] = {bw1, bw2, bw3};
            src = bws[l];
            dh = bbH + 2048 + l * 16384;
            dl = bbL + 2048 + l * 16384;
            K = 128; N = 128; KD = 128;
            k0 = (tile >> 2) * 32; n0 = (tile & 3) * 32;
        }
    } else {
        const int t = id - 52;
        const int e = t / 56, r = t % 56;
        if (r < 48) {
            const int l = r / 16, tile = r % 16;
            const float* hws[3] = {hw0, hw1, hw2};
            src = hws[l] + (size_t)e * 16384;
            dh = hH + (size_t)e * HWE_F16 + l * 16384;
            dl = hL + (size_t)e * HWE_F16 + l * 16384;
            K = 128; N = 128; KD = 128;
            k0 = (tile >> 2) * 32; n0 = (tile & 3) * 32;
        } else {
            const int r2 = r - 48;
            src = hw3 + (size_t)e * 8192;
            dh = hH + (size_t)e * HWE_F16 + 49152;
            dl = hL + (size_t)e * HWE_F16 + 49152;
            K = 128; N = 64; KD = 128;
            k0 = (r2 >> 1) * 32; n0 = (r2 & 1) * 32;
        }
    }

    const int c = tx & 31, g = tx >> 5;
#pragma unroll
    for (int i = 0; i < 4; ++i) {
        const int row = g * 4 + i;
        if (k0 + row < K)
            T[c][row] = src[(size_t)(k0 + row) * N + n0 + c];   // T[n-local][k-local]
    }
    __syncthreads();
#pragma unroll
    for (int i = 0; i < 4; ++i) {
        const int n = g * 4 + i;
        if (k0 + c < K) {
            const float v = T[n][c];
            const f16 hi = (f16)v;
            dh[(size_t)(n0 + n) * KD + k0 + c] = hi;
            dl[(size_t)(n0 + n) * KD + k0 + c] = (f16)((v - (float)hi) * 1024.0f);
        }
    }
}

// ---------------------------------------------------------------------------
extern "C" void kernel_launch(void* const* d_in, const int* in_sizes, int n_in,
                              void* d_out, int out_size, void* d_ws, size_t ws_size,
                              hipStream_t stream)
{
    const float* z   = (const float*)d_in[0];
    const int*   y   = (const int*)d_in[1];
    const float* bw0 = (const float*)d_in[2];
    const float* bb0 = (const float*)d_in[3];
    const float* bw1 = (const float*)d_in[4];
    const float* bb1 = (const float*)d_in[5];
    const float* bw2 = (const float*)d_in[6];
    const float* bb2 = (const float*)d_in[7];
    const float* bw3 = (const float*)d_in[8];
    const float* bb3 = (const float*)d_in[9];
    const float* hw0 = (const float*)d_in[10];
    const float* hb0 = (const float*)d_in[11];
    const float* hw1 = (const float*)d_in[12];
    const float* hb1 = (const float*)d_in[13];
    const float* hw2 = (const float*)d_in[14];
    const float* hb2 = (const float*)d_in[15];
    const float* hw3 = (const float*)d_in[16];
    const float* hb3 = (const float*)d_in[17];
    float* out = (float*)d_out;

    // h (f16 [B][128], 16.78 MB) aliases d_out exactly: sample b's h row and
    // out row occupy the same 256-byte range; gather precedes store per block.
    f16* hHi = (f16*)d_out;

    // workspace layout (all segments 256B-multiple)
    char* p = (char*)d_ws;
    f16* bbH = (f16*)p;  p += (size_t)BBW_F16 * 2;           // 102,400 B
    f16* bbL = (f16*)p;  p += (size_t)BBW_F16 * 2;
    f16* hH  = (f16*)p;  p += (size_t)Kc * HWE_F16 * 2;      // 1.835 MB
    f16* hL  = (f16*)p;  p += (size_t)Kc * HWE_F16 * 2;
    int* idx = (int*)p;  p += (size_t)Kc * CAP * 4;          // 294,912 B
    int* cursor = (int*)p;

    prep_w<<<52 + Kc * 56, 256, 0, stream>>>(bw0, bw1, bw2, bw3,
                                             hw0, hw1, hw2, hw3,
                                             bbH, bbL, hH, hL, cursor);

    backbone_mfma<<<Bc / SB, 256, 0, stream>>>(z, y, bbH, bbL,
                                               bb0, bb1, bb2, bb3,
                                               hHi, idx, cursor);

    heads_mfma<<<NBLK, 256, 0, stream>>>(hHi, idx, cursor,
                                         hH, hL, hb0, hb1, hb2, hb3, out);
}